// Round 16
// baseline (561.954 us; speedup 1.0000x reference)
//
#include <hip/hip_runtime.h>
#include <hip/hip_bf16.h>

typedef __attribute__((ext_vector_type(4))) float f32x4;
typedef __attribute__((ext_vector_type(8))) short s16x8;
typedef __attribute__((ext_vector_type(2))) unsigned int u32x2;
typedef __attribute__((ext_vector_type(4))) unsigned int u32x4;

#define DEV static __device__ __forceinline__

constexpr int Tn = 256, Bn = 1024, Sn = 8;
constexpr float L2E   =  1.44269504f;
constexpr float NL2E  = -1.44269504f;   // fold into sigmoid-arg weights
constexpr float N2L2E = -2.88539008f;   // fold into tanh-arg weights

struct Params {
  const float* obs; const float* enc_w; const float* enc_b;
  const float* mw[15];            // wW wI wA zW zI zA rW rI rA hW hI hA aW aI aA
  const float* gw[4];             // att wmg img amg  [32 x 64]
  const float* gb[4];
  const float* z_b; const float* r_b; const float* h_b; const float* a_b;
  const float* phi_w; const float* phi_b;
  float* out;
};

DEV f32x4 ld4(const float* p) { return *(const f32x4*)p; }
DEV f32x4 zero4() { f32x4 r = {0.f,0.f,0.f,0.f}; return r; }
DEV s16x8 zero8() { s16x8 r = {0,0,0,0,0,0,0,0}; return r; }

DEV unsigned cvtpk(float a, float b) {
  __hip_bfloat162 t = __float22bfloat162_rn(make_float2(a, b));
  unsigned u; __builtin_memcpy(&u, &t, 4);
  return u;
}

// pack 8 scaled f32 into a bf16x8 fragment; elem e=0..3 <-> k=4h+e,
// e=4..7 <-> k=16+4h+(e-4)  [k-map lambda, identical on A and B sides]
DEV s16x8 pk2s(f32x4 a, f32x4 b, float s) {
  u32x4 f;
  f[0] = cvtpk(a[0]*s, a[1]*s); f[1] = cvtpk(a[2]*s, a[3]*s);
  f[2] = cvtpk(b[0]*s, b[1]*s); f[3] = cvtpk(b[2]*s, b[3]*s);
  s16x8 r; __builtin_memcpy(&r, &f, 16);
  return r;
}

// weight fragment (A-operand of swapped MFMA), pre-scaled by s
DEV s16x8 wfrag(const float* w, int row, int ldk, int kofs, int h, float s) {
  const float* p = w + row*ldk + kofs + 4*h;
  return pk2s(ld4(p), ld4(p+16), s);
}

DEV f32x4 MF(s16x8 a, s16x8 b, f32x4 c) {
  return __builtin_amdgcn_mfma_f32_16x16x32_bf16(a, b, c, 0, 0, 0);
}

DEV float ex2(float x)  { return __builtin_amdgcn_exp2f(x); }
DEV float rcp_(float x) { return __builtin_amdgcn_rcpf(x); }
DEV float sg(float a) { return rcp_(1.f + ex2(a)); }                  // sigmoid(x), a=-L2E*x
DEV float th(float a) { return fmaf(rcp_(1.f + ex2(a)), 2.f, -1.f); } // tanh(x), a=-2L2E*x

DEV unsigned long long pack64(u32x2 v) {
  return ((unsigned long long)v[1] << 32) | v[0];
}
DEV u32x2 unpack64(unsigned long long x) {
  u32x2 r; r[0] = (unsigned)x; r[1] = (unsigned)(x >> 32); return r;
}
DEV u32x2 pkx(f32x4 v) {
  u32x2 r; r[0] = cvtpk(v[0], v[1]); r[1] = cvtpk(v[2], v[3]); return r;
}
DEV s16x8 frag(u32x2 own, u32x2 oth, int wv) {
  u32x4 f;
  if (wv == 0) { f[0]=own[0]; f[1]=own[1]; f[2]=oth[0]; f[3]=oth[1]; }
  else         { f[0]=oth[0]; f[1]=oth[1]; f[2]=own[0]; f[3]=own[1]; }
  s16x8 r; __builtin_memcpy(&r, &f, 16);
  return r;
}

DEV f32x4 scl4(f32x4 v, float s) { f32x4 r; r[0]=v[0]*s; r[1]=v[1]*s; r[2]=v[2]*s; r[3]=v[3]*s; return r; }

// 2 waves/block, TWO independent batch groups (A,B) per wave-pair, interleaved
// at STATEMENT granularity: every MFMA/act/pack appears as adjacent A,B ops so
// the in-order issue unit fills chain-A stalls with chain-B work (round-10's
// coarse-block version serialized; this is the fine-grained retry). The 4
// exchanges per step are SHARED: both groups' halves written before one
// barrier -> per-group sync cost halves. Weights/biases shared across groups.
__global__ __launch_bounds__(128, 1) void anima_kernel(Params P) {
  const int tid  = threadIdx.x;
  const int wv   = tid >> 6;
  const int lane = tid & 63;
  const int h = lane >> 4, c = lane & 15;
  const int bbase = blockIdx.x * 32;          // group A: +c, group B: +16+c
  const int row = wv*16 + c;

  __shared__ unsigned long long xb[4][2][128];

  const float msc[15] = {N2L2E,N2L2E,N2L2E,  NL2E,NL2E,NL2E,  NL2E,NL2E,NL2E,
                         N2L2E,N2L2E,N2L2E,  N2L2E,N2L2E,N2L2E};
  s16x8 m[15];
#pragma unroll
  for (int i = 0; i < 15; ++i) m[i] = wfrag(P.mw[i], row, 32, 0, h, msc[i]);

  s16x8 g[4][2];
#pragma unroll
  for (int i = 0; i < 4; ++i)
#pragma unroll
    for (int q = 0; q < 2; ++q)
      g[i][q] = wfrag(P.gw[i], row, 64, 32*q, h, NL2E);

  s16x8 ef = zero8();
  if (h < 2) { f32x4 v = ld4(P.enc_w + row*Sn + 4*h); ef = pk2s(v, zero4(), N2L2E); }

  s16x8 pf = (wv == 0 && c < 4) ? wfrag(P.phi_w, c, 32, 0, h, 1.0f) : zero8();

  const int o = wv*16 + 4*h;
  f32x4 bE  = scl4(ld4(P.enc_b + o), N2L2E);
  f32x4 bAt = scl4(ld4(P.gb[0] + o), NL2E);
  f32x4 bMu = scl4(ld4(P.gb[1] + o), NL2E);
  f32x4 bMI = scl4(ld4(P.gb[2] + o), NL2E);
  f32x4 bMA = scl4(ld4(P.gb[3] + o), NL2E);
  f32x4 bZ  = scl4(ld4(P.z_b + o),  NL2E);
  f32x4 bR  = scl4(ld4(P.r_b + o),  NL2E);
  f32x4 bH  = scl4(ld4(P.h_b + o),  N2L2E);
  f32x4 bA  = scl4(ld4(P.a_b + o),  N2L2E);
  f32x4 pb  = (wv == 0 && h == 0) ? ld4(P.phi_b) : zero4();

  // ---- per-group state ----
  f32x4 ivA = zero4(), ivB = zero4();
  s16x8 InfA = zero8(), InfB = zero8();
  u32x2 an2A; an2A[0]=0u; an2A[1]=0u;
  u32x2 an2B; an2B[0]=0u; an2B[1]=0u;

  f32x4 obA = zero4(), obB = zero4(), obNA = zero4(), obNB = zero4();
  if (h < 2) {
    obA  = ld4(P.obs + (size_t)(bbase + c) * Sn + 4*h);
    obB  = ld4(P.obs + (size_t)(bbase + 16 + c) * Sn + 4*h);
    obNA = ld4(P.obs + ((size_t)1*Bn + bbase + c) * Sn + 4*h);
    obNB = ld4(P.obs + ((size_t)1*Bn + bbase + 16 + c) * Sn + 4*h);
  }
  s16x8 OfA = (h < 2) ? pk2s(obA, zero4(), 1.0f) : zero8();
  s16x8 OfB = (h < 2) ? pk2s(obB, zero4(), 1.0f) : zero8();

  // ---- early-A partials for t=0 (zero states => exact) ----
  f32x4 tA1A = zero4(), tA1B = zero4();
  f32x4 yAtA = bAt,     yAtB = bAt;
  f32x4 uMuA = bMu,     uMuB = bMu;
  f32x4 aEA  = MF(ef, OfA, bE);
  f32x4 aEB  = MF(ef, OfB, bE);

  xb[3][0][tid] = pack64(an2A);
  xb[3][1][tid] = pack64(an2B);
  __syncthreads();
  unsigned long long pw3A = xb[3][0][tid ^ 64];
  unsigned long long pw3B = xb[3][1][tid ^ 64];

#pragma unroll 1
  for (int t = 0; t < Tn; ++t) {
    // ---- finish phase A: A(t-1) arrives ----
    s16x8 AnfA = frag(an2A, unpack64(pw3A), wv);
    s16x8 AnfB = frag(an2B, unpack64(pw3B), wv);
    if (wv == 0 && t) {
      f32x4 aPA = MF(pf, AnfA, pb);
      f32x4 aPB = MF(pf, AnfB, pb);
      if (h == 0) {
        *(f32x4*)(P.out + ((size_t)(t-1)*Bn + bbase + c) * 4) = aPA;
        *(f32x4*)(P.out + ((size_t)(t-1)*Bn + bbase + 16 + c) * 4) = aPB;
      }
    }
    f32x4 aWlA = MF(m[2], AnfA, tA1A);
    f32x4 aWlB = MF(m[2], AnfB, tA1B);
    f32x4 aMuA = MF(g[1][1], AnfA, uMuA);
    f32x4 aMuB = MF(g[1][1], AnfB, uMuB);
    f32x4 wnA, wnB;
#pragma unroll
    for (int r = 0; r < 4; ++r) {
      float etpA = fmaf(rcp_(1.f + ex2(aEA[r])), -4.f*L2E, 2.f*L2E);
      float etpB = fmaf(rcp_(1.f + ex2(aEB[r])), -4.f*L2E, 2.f*L2E);
      float atA  = sg(yAtA[r]);
      float atB  = sg(yAtB[r]);
      float mgA  = sg(aMuA[r]);
      float mgB  = sg(aMuB[r]);
      wnA[r] = th(fmaf(etpA, atA, aWlA[r]*mgA));
      wnB[r] = th(fmaf(etpB, atB, aWlB[r]*mgB));
    }
    u32x2 wn2A = pkx(wnA);
    u32x2 wn2B = pkx(wnB);
    xb[0][0][tid] = pack64(wn2A);
    xb[0][1][tid] = pack64(wn2B);
    __syncthreads();
    unsigned long long pw0A = xb[0][0][tid ^ 64];
    unsigned long long pw0B = xb[0][1][tid ^ 64];
    f32x4 eZA  = MF(m[5], AnfA, MF(m[4], InfA, bZ));   // fill read latency
    f32x4 eZB  = MF(m[5], AnfB, MF(m[4], InfB, bZ));
    f32x4 eRA  = MF(m[8], AnfA, MF(m[7], InfA, bR));
    f32x4 eRB  = MF(m[8], AnfB, MF(m[7], InfB, bR));
    f32x4 eMIA = MF(g[2][1], AnfA, bMI);
    f32x4 eMIB = MF(g[2][1], AnfB, bMI);
    s16x8 WnewA = frag(wn2A, unpack64(pw0A), wv);
    s16x8 WnewB = frag(wn2B, unpack64(pw0B), wv);
    f32x4 aZA  = MF(m[3], WnewA, eZA);
    f32x4 aZB  = MF(m[3], WnewB, eZB);
    f32x4 aRA  = MF(m[6], WnewA, eRA);
    f32x4 aRB  = MF(m[6], WnewB, eRB);
    f32x4 aMIA = MF(g[2][0], WnewA, eMIA);
    f32x4 aMIB = MF(g[2][0], WnewB, eMIB);
    f32x4 zzA, riA, miA, zzB, riB, miB;
#pragma unroll
    for (int r = 0; r < 4; ++r) {
      zzA[r] = sg(aZA[r]);        zzB[r] = sg(aZB[r]);
      riA[r] = sg(aRA[r]) * ivA[r]; riB[r] = sg(aRB[r]) * ivB[r];
      miA[r] = sg(aMIA[r]);       miB[r] = sg(aMIB[r]);
    }
    u32x2 ri2A = pkx(riA);
    u32x2 ri2B = pkx(riB);
    xb[1][0][tid] = pack64(ri2A);
    xb[1][1][tid] = pack64(ri2B);
    __syncthreads();
    unsigned long long pw1A = xb[1][0][tid ^ 64];
    unsigned long long pw1B = xb[1][1][tid ^ 64];
    f32x4 eHA  = MF(m[11], AnfA, MF(m[9],  WnewA, bH));  // fill
    f32x4 eHB  = MF(m[11], AnfB, MF(m[9],  WnewB, bH));
    f32x4 eAlA = MF(m[14], AnfA, MF(m[12], WnewA, bA));
    f32x4 eAlB = MF(m[14], AnfB, MF(m[12], WnewB, bA));
    f32x4 eMAA = MF(g[3][0], WnewA, bMA);
    f32x4 eMAB = MF(g[3][0], WnewB, bMA);
    s16x8 rIfA = frag(ri2A, unpack64(pw1A), wv);
    s16x8 rIfB = frag(ri2B, unpack64(pw1B), wv);
    f32x4 aHA = MF(m[10], rIfA, eHA);
    f32x4 aHB = MF(m[10], rIfB, eHB);
    f32x4 inwA, inwB;
#pragma unroll
    for (int r = 0; r < 4; ++r) {
      float hvA = th(aHA[r]);
      float hvB = th(aHB[r]);
      inwA[r] = fmaf(zzA[r], hvA * miA[r] - ivA[r], ivA[r]);
      inwB[r] = fmaf(zzB[r], hvB * miB[r] - ivB[r], ivB[r]);
    }
    u32x2 in2A = pkx(inwA);
    u32x2 in2B = pkx(inwB);
    xb[2][0][tid] = pack64(in2A);
    xb[2][1][tid] = pack64(in2B);
    __syncthreads();
    unsigned long long pw2A = xb[2][0][tid ^ 64];
    unsigned long long pw2B = xb[2][1][tid ^ 64];
    f32x4 t0A = MF(m[0], WnewA, zero4());                // fill: next-A W-parts
    f32x4 t0B = MF(m[0], WnewB, zero4());
    f32x4 y0A = MF(g[0][0], WnewA, bAt);
    f32x4 y0B = MF(g[0][0], WnewB, bAt);
    s16x8 OfNA = (h < 2) ? pk2s(obNA, zero4(), 1.0f) : zero8();
    s16x8 OfNB = (h < 2) ? pk2s(obNB, zero4(), 1.0f) : zero8();
    aEA = MF(ef, OfNA, bE);
    aEB = MF(ef, OfNB, bE);
    s16x8 InewA = frag(in2A, unpack64(pw2A), wv);
    s16x8 InewB = frag(in2B, unpack64(pw2B), wv);
    f32x4 aAlA = MF(m[13], InewA, eAlA);
    f32x4 aAlB = MF(m[13], InewB, eAlB);
    f32x4 aMAA = MF(g[3][1], InewA, eMAA);
    f32x4 aMAB = MF(g[3][1], InewB, eMAB);
    f32x4 anA, anB;
#pragma unroll
    for (int r = 0; r < 4; ++r) {
      anA[r] = th(aAlA[r] * sg(aMAA[r]));
      anB[r] = th(aAlB[r] * sg(aMAB[r]));
    }
    an2A = pkx(anA);
    an2B = pkx(anB);
    xb[3][0][tid] = pack64(an2A);
    xb[3][1][tid] = pack64(an2B);
    __syncthreads();
    pw3A = xb[3][0][tid ^ 64];
    pw3B = xb[3][1][tid ^ 64];
    tA1A = MF(m[1], InewA, t0A);                         // fill: next-A I-parts
    tA1B = MF(m[1], InewB, t0B);
    yAtA = MF(g[0][1], InewA, y0A);
    yAtB = MF(g[0][1], InewB, y0B);
    uMuA = MF(g[1][0], InewA, bMu);
    uMuB = MF(g[1][0], InewB, bMu);
    if (h < 2 && t + 2 < Tn) {
      obNA = ld4(P.obs + ((size_t)(t+2)*Bn + bbase + c) * Sn + 4*h);
      obNB = ld4(P.obs + ((size_t)(t+2)*Bn + bbase + 16 + c) * Sn + 4*h);
    }
    InfA = InewA; ivA = inwA;
    InfB = InewB; ivB = inwB;
  }

  // ---- epilogue: phi(A(Tn-1)) ----
  s16x8 AnfA = frag(an2A, unpack64(pw3A), wv);
  s16x8 AnfB = frag(an2B, unpack64(pw3B), wv);
  if (wv == 0) {
    f32x4 aPA = MF(pf, AnfA, pb);
    f32x4 aPB = MF(pf, AnfB, pb);
    if (h == 0) {
      *(f32x4*)(P.out + ((size_t)(Tn-1)*Bn + bbase + c) * 4) = aPA;
      *(f32x4*)(P.out + ((size_t)(Tn-1)*Bn + bbase + 16 + c) * 4) = aPB;
    }
  }
}

extern "C" void kernel_launch(void* const* d_in, const int* in_sizes, int n_in,
                              void* d_out, int out_size, void* d_ws, size_t ws_size,
                              hipStream_t stream) {
  (void)in_sizes; (void)n_in; (void)d_ws; (void)ws_size; (void)out_size;
  Params p;
  p.obs   = (const float*)d_in[0];
  p.enc_w = (const float*)d_in[1];
  p.enc_b = (const float*)d_in[2];
  for (int i = 0; i < 15; ++i) p.mw[i] = (const float*)d_in[3 + i];
  for (int i = 0; i < 4; ++i) {
    p.gw[i] = (const float*)d_in[18 + 2*i];
    p.gb[i] = (const float*)d_in[19 + 2*i];
  }
  p.z_b   = (const float*)d_in[26];
  p.r_b   = (const float*)d_in[27];
  p.h_b   = (const float*)d_in[28];
  p.a_b   = (const float*)d_in[29];
  p.phi_w = (const float*)d_in[30];
  p.phi_b = (const float*)d_in[31];
  p.out   = (float*)d_out;

  hipLaunchKernelGGL(anima_kernel, dim3(Bn / 32), dim3(128), 0, stream, p);
}